// Round 1
// baseline (765.247 us; speedup 1.0000x reference)
//
#include <hip/hip_runtime.h>
#include <stdint.h>

// Problem constants
#define N_TOK  4096
#define D_DIM  1024
#define R_ROWS 10000
#define R_PAD  10240
#define V_OUT  32000

typedef __attribute__((ext_vector_type(8))) short bf16x8;
typedef __attribute__((ext_vector_type(4))) float f32x4;

// fp32 -> bf16 round-to-nearest-even (inputs are finite normals)
__device__ __forceinline__ uint32_t f2bf(float x) {
    uint32_t u = __float_as_uint(x);
    return (u + 0x7FFFu + ((u >> 16) & 1u)) >> 16;
}
__device__ __forceinline__ float bf2f(uint32_t lo16) {
    return __uint_as_float(lo16 << 16);
}

// ---------------- conversion kernels ----------------
__global__ __launch_bounds__(256) void cvt_ins_kernel(const float* __restrict__ in,
                                                      uint16_t* __restrict__ outb) {
    int i = blockIdx.x * 256 + threadIdx.x;       // one thread per 4 floats
    float4 f = reinterpret_cast<const float4*>(in)[i];
    uint32_t lo = f2bf(f.x) | (f2bf(f.y) << 16);
    uint32_t hi = f2bf(f.z) | (f2bf(f.w) << 16);
    reinterpret_cast<uint2*>(outb)[i] = make_uint2(lo, hi);
}

__global__ __launch_bounds__(256) void cvt_w_kernel(const float* __restrict__ W,
                                                    uint16_t* __restrict__ Wb) {
    int i = blockIdx.x * 256 + threadIdx.x;       // one thread per 4 floats
    int row = i >> 8;                             // 256 quads per 1024-wide row
    uint32_t lo = 0, hi = 0;
    if (row < R_ROWS) {
        float4 f = reinterpret_cast<const float4*>(W)[i];
        lo = f2bf(f.x) | (f2bf(f.y) << 16);
        hi = f2bf(f.z) | (f2bf(f.w) << 16);
    }
    reinterpret_cast<uint2*>(Wb)[i] = make_uint2(lo, hi);
}

// ---------------- GEMM: PT[r, n] = sum_d W[r,d] * ins[n,d] ----------------
// A = W_bf [R_PAD][D_DIM], B = ins_bf [N_TOK][D_DIM], C = PT [R_PAD][N_TOK] bf16
// m97 structure: 128x128 tile, BK=64, global_load_lds width 16, 2 barriers/K-step.
__global__ __launch_bounds__(256) void gemm_bt_kernel(const uint16_t* __restrict__ A,
                                                      const uint16_t* __restrict__ B,
                                                      uint16_t* __restrict__ C) {
    __shared__ uint16_t As[128 * 64];
    __shared__ uint16_t Bs[128 * 64];

    const int t   = threadIdx.x;
    const int l   = t & 63;
    const int wid = t >> 6;
    const int wr  = wid >> 1;          // wave row (0..1)
    const int wc  = wid & 1;           // wave col (0..1)
    const int bm  = blockIdx.y;        // over R_PAD/128 = 80
    const int bn  = blockIdx.x;        // over N_TOK/128 = 32
    const int fr  = l & 15;            // fragment row/col
    const int ko  = (l >> 4) * 8;      // k offset within 32

    f32x4 acc[4][4];
#pragma unroll
    for (int mi = 0; mi < 4; ++mi)
#pragma unroll
        for (int ni = 0; ni < 4; ++ni)
            acc[mi][ni] = (f32x4){0.f, 0.f, 0.f, 0.f};

    // staging map: thread t loads 16B; rows t>>3 within a 32-row slab
    const int r_stage = t >> 3;               // 0..31
    const int c_stage = (t & 7) * 8;          // element offset (16B chunks)
    const uint16_t* Ag = A + (size_t)(bm * 128 + r_stage) * D_DIM + c_stage;
    const uint16_t* Bg = B + (size_t)(bn * 128 + r_stage) * D_DIM + c_stage;
    uint16_t* As_p = As + r_stage * 64 + c_stage;
    uint16_t* Bs_p = Bs + r_stage * 64 + c_stage;

    for (int kt = 0; kt < D_DIM / 64; ++kt) {
        const uint16_t* ag = Ag + kt * 64;
        const uint16_t* bg = Bg + kt * 64;
#pragma unroll
        for (int i = 0; i < 4; ++i) {
            __builtin_amdgcn_global_load_lds(
                (const __attribute__((address_space(1))) void*)(ag + (size_t)i * 32 * D_DIM),
                (__attribute__((address_space(3))) void*)(As_p + i * 32 * 64), 16, 0, 0);
            __builtin_amdgcn_global_load_lds(
                (const __attribute__((address_space(1))) void*)(bg + (size_t)i * 32 * D_DIM),
                (__attribute__((address_space(3))) void*)(Bs_p + i * 32 * 64), 16, 0, 0);
        }
        __syncthreads();   // drains vmcnt(0): staged data visible
#pragma unroll
        for (int ks = 0; ks < 2; ++ks) {
            bf16x8 a[4], b[4];
#pragma unroll
            for (int mi = 0; mi < 4; ++mi)
                a[mi] = *reinterpret_cast<const bf16x8*>(
                    &As[(wr * 64 + mi * 16 + fr) * 64 + ks * 32 + ko]);
#pragma unroll
            for (int ni = 0; ni < 4; ++ni)
                b[ni] = *reinterpret_cast<const bf16x8*>(
                    &Bs[(wc * 64 + ni * 16 + fr) * 64 + ks * 32 + ko]);
#pragma unroll
            for (int mi = 0; mi < 4; ++mi)
#pragma unroll
                for (int ni = 0; ni < 4; ++ni)
                    acc[mi][ni] = __builtin_amdgcn_mfma_f32_16x16x32_bf16(
                        a[mi], b[ni], acc[mi][ni], 0, 0, 0);
        }
        __syncthreads();   // protect LDS before next stage
    }

    // epilogue: C/D layout col = l&15, row = (l>>4)*4 + j
    const int orow0 = bm * 128 + wr * 64 + (l >> 4) * 4;
    const int ocol0 = bn * 128 + wc * 64 + (l & 15);
#pragma unroll
    for (int mi = 0; mi < 4; ++mi)
#pragma unroll
        for (int ni = 0; ni < 4; ++ni)
#pragma unroll
            for (int j = 0; j < 4; ++j) {
                int row = orow0 + mi * 16 + j;
                int col = ocol0 + ni * 16;
                C[(size_t)row * N_TOK + col] = (uint16_t)f2bf(acc[mi][ni][j]);
            }
}

// ---------------- epilogue: out[n,v] = sum_k val[v,k]*PT[idx[v,k], n] + b_eff[v] ----
// Tile: 128 n x 64 v. Phase A: lanes<->n, coalesced PT row reads, LDS transpose.
// Phase B: lanes<->v, coalesced float4 output writes.
__global__ __launch_bounds__(256) void epilogue_kernel(const uint16_t* __restrict__ PT,
                                                       const int* __restrict__ code_idx,
                                                       const float* __restrict__ code_val,
                                                       const float* __restrict__ bias,
                                                       float* __restrict__ out) {
    __shared__ float tile[64][129];   // [v_local][n_local], pad 129 (phase-B ~2-way)

    const int t  = threadIdx.x;
    const int l  = t & 63;
    const int w  = t >> 6;
    const int n0 = blockIdx.y * 128;
    const int v0 = blockIdx.x * 64;

    for (int it = 0; it < 16; ++it) {
        const int vl = it * 4 + w;            // 0..63
        const int v  = v0 + vl;
        const int i0 = code_idx[2 * v + 0];
        const int i1 = code_idx[2 * v + 1];
        const float c0 = code_val[2 * v + 0];
        const float c1 = code_val[2 * v + 1];
        const float be = c0 * bias[i0] + c1 * bias[i1];

        // two bf16 (n = 2l, 2l+1) per gathered row: 4B/lane, 256B/wave, coalesced
        uint32_t p0 = *reinterpret_cast<const uint32_t*>(&PT[(size_t)i0 * N_TOK + n0 + 2 * l]);
        uint32_t p1 = *reinterpret_cast<const uint32_t*>(&PT[(size_t)i1 * N_TOK + n0 + 2 * l]);

        float o0 = c0 * bf2f(p0 & 0xFFFFu) + c1 * bf2f(p1 & 0xFFFFu) + be;
        float o1 = c0 * bf2f(p0 >> 16)     + c1 * bf2f(p1 >> 16)     + be;
        tile[vl][2 * l + 0] = o0;
        tile[vl][2 * l + 1] = o1;
    }
    __syncthreads();

#pragma unroll
    for (int rr = 0; rr < 8; ++rr) {
        const int n  = rr * 16 + (t >> 4);    // 0..127
        const int vq = (t & 15) * 4;
        float4 o;
        o.x = tile[vq + 0][n];
        o.y = tile[vq + 1][n];
        o.z = tile[vq + 2][n];
        o.w = tile[vq + 3][n];
        *reinterpret_cast<float4*>(&out[(size_t)(n0 + n) * V_OUT + v0 + vq]) = o;
    }
}

// ---------------- launch ----------------
extern "C" void kernel_launch(void* const* d_in, const int* in_sizes, int n_in,
                              void* d_out, int out_size, void* d_ws, size_t ws_size,
                              hipStream_t stream) {
    const float* ins      = (const float*)d_in[0];   // [4096,1024]
    const float* W        = (const float*)d_in[1];   // [10000,1024]
    const float* b        = (const float*)d_in[2];   // [10000]
    const int* code_idx   = (const int*)d_in[3];     // [32000,2]
    const float* code_val = (const float*)d_in[4];   // [32000,2]
    float* out            = (float*)d_out;           // [4096,32000]

    uint8_t* ws = (uint8_t*)d_ws;
    uint16_t* ins_bf = (uint16_t*)(ws);                         //  8,388,608 B
    uint16_t* W_bf   = (uint16_t*)(ws + 8388608);               // 20,971,520 B
    uint16_t* PT     = (uint16_t*)(ws + 8388608 + 20971520);    // 83,886,080 B
    // total ws use: ~113.2 MB

    cvt_ins_kernel<<<(N_TOK * D_DIM / 4) / 256, 256, 0, stream>>>(ins, ins_bf);
    cvt_w_kernel<<<(R_PAD * D_DIM / 4) / 256, 256, 0, stream>>>(W, W_bf);
    gemm_bt_kernel<<<dim3(N_TOK / 128, R_PAD / 128), 256, 0, stream>>>(W_bf, ins_bf, PT);
    epilogue_kernel<<<dim3(V_OUT / 64, N_TOK / 128), 256, 0, stream>>>(PT, code_idx, code_val, b, out);
}